// Round 3
// baseline (4031.911 us; speedup 1.0000x reference)
//
#include <hip/hip_runtime.h>
#include <cstdint>
#include <cstddef>

#define TSTEPS 100
#define NB 256
#define INF 2312
#define HIDN 512
#define NOUT 10

// ws layout (float offsets)
#define OFF_WT 0                  // 262144 floats (w_rec transposed)
#define OFF_CI 262144             // 13107200 floats (input-projection cache)
#define WS_FLOATS 13369344        // 53.5 MB

// build w_recT[r][h] = w_rec[h][r]
__global__ __launch_bounds__(256) void init_kernel(float* __restrict__ wT,
                                                   const float* __restrict__ w_rec) {
    int m = blockIdx.x * 256 + threadIdx.x;   // m = r*512 + h
    if (m < HIDN * HIDN) {
        int r = m >> 9, h = m & 511;
        wT[m] = w_rec[h * HIDN + r];
    }
}

// C[r][h] = sum_k X[r][k] * Win[h][k], fp64 accumulate, fp32 store.
// M=25600, N=512, K=2312. 64x64 tile, 256 threads, 4x4 micro-tile.
// VERBATIM from the R1-passing kernel: per-element fp64 op order must not change
// (downstream dynamics are chaotic; spike pattern must match numpy's ulp-for-ulp).
__global__ __launch_bounds__(256) void gemm_in(const float* __restrict__ X,
                                               const float* __restrict__ Win,
                                               float* __restrict__ C) {
    __shared__ float As[32][68];   // [k][row], padded
    __shared__ float Bs[32][68];
    const int tid = threadIdx.x;
    const int ty = tid >> 4, tx = tid & 15;
    const int row0 = blockIdx.y * 64, col0 = blockIdx.x * 64;
    const int lr = tid >> 2;            // 0..63
    const int lc = (tid & 3) * 8;       // 0,8,16,24
    double acc[4][4] = {};
    for (int k0 = 0; k0 < INF; k0 += 32) {
        __syncthreads();
#pragma unroll
        for (int q = 0; q < 2; ++q) {
            int kc = lc + q * 4;
            int gk = k0 + kc;
            float4 va, vb;
            if (gk < INF) {   // INF%4==0 and gk%4==0 -> fully in-bounds
                va = *(const float4*)(X + (size_t)(row0 + lr) * INF + gk);
                vb = *(const float4*)(Win + (size_t)(col0 + lr) * INF + gk);
            } else {
                va = make_float4(0.f, 0.f, 0.f, 0.f);
                vb = va;
            }
            As[kc + 0][lr] = va.x; As[kc + 1][lr] = va.y;
            As[kc + 2][lr] = va.z; As[kc + 3][lr] = va.w;
            Bs[kc + 0][lr] = vb.x; Bs[kc + 1][lr] = vb.y;
            Bs[kc + 2][lr] = vb.z; Bs[kc + 3][lr] = vb.w;
        }
        __syncthreads();
#pragma unroll 8
        for (int kk = 0; kk < 32; ++kk) {
            float4 a4 = *(const float4*)&As[kk][ty * 4];
            float4 b4 = *(const float4*)&Bs[kk][tx * 4];
            double ad[4] = {(double)a4.x, (double)a4.y, (double)a4.z, (double)a4.w};
            double bd[4] = {(double)b4.x, (double)b4.y, (double)b4.z, (double)b4.w};
#pragma unroll
            for (int i = 0; i < 4; ++i)
#pragma unroll
                for (int j = 0; j < 4; ++j)
                    acc[i][j] += ad[i] * bd[j];
        }
    }
#pragma unroll
    for (int i = 0; i < 4; ++i) {
        float4 o;
        o.x = (float)acc[i][0]; o.y = (float)acc[i][1];
        o.z = (float)acc[i][2]; o.w = (float)acc[i][3];
        *(float4*)(C + (size_t)(row0 + ty * 4 + i) * HIDN + col0 + tx * 4) = o;
    }
}

// All 100 timesteps fused. Block = one batch (256 blocks), 512 threads = one h each.
// State: pos in registers, LI v/isyn in lane-0 registers, z via LDS ballot words.
// Numerics: identical op sequence to the R1 step kernel (per-word ascending bit-pop,
// fp32 per-word partials summed in fp64 in word order, __f*_rn elementwise chain).
__global__ __launch_bounds__(512) void fused_steps(const float* __restrict__ ci,
        const float* __restrict__ wT, const float* __restrict__ w_out,
        float* __restrict__ out) {
    __shared__ unsigned long long zbuf[2][8];
    __shared__ float wout_s[NOUT * HIDN];   // 20 KB
    const int tid = threadIdx.x;
    const int wv = tid >> 6, lane = tid & 63;
    const int b = blockIdx.x;
    const int h = tid;

    for (int i = tid; i < NOUT * HIDN; i += 512) wout_s[i] = w_out[i];
    if (tid < 16) ((unsigned long long*)zbuf)[tid] = 0ull;
    float pos = 0.0f;
    // LI state held by lane 0 of each wave: o=wv, and o=8+wv for wv<2
    float v0 = 0.f, i0 = 0.f, v1 = 0.f, i1 = 0.f;
    __syncthreads();

    for (int t = 0; t < TSTEPS; ++t) {
        // ---- recurrent gather using z from step t-1 (buffer (t+1)&1) ----
        unsigned long long m[8];
#pragma unroll
        for (int c = 0; c < 8; ++c) {
            unsigned long long w = zbuf[(t + 1) & 1][c];
            unsigned int lo = __builtin_amdgcn_readfirstlane((unsigned int)w);
            unsigned int hi = __builtin_amdgcn_readfirstlane((unsigned int)(w >> 32));
            m[c] = ((unsigned long long)hi << 32) | lo;
        }
        float f[8] = {0.f, 0.f, 0.f, 0.f, 0.f, 0.f, 0.f, 0.f};
        // 8 independent pop-chains (ILP); per-word bit order ascending = same as
        // R1's lo-then-hi ascending consumption.
        bool any = (m[0] | m[1] | m[2] | m[3] | m[4] | m[5] | m[6] | m[7]) != 0ull;
        while (any) {
            any = false;
#pragma unroll
            for (int c = 0; c < 8; ++c) {
                if (m[c]) {
                    int bit = __builtin_ctzll(m[c]);
                    m[c] &= m[c] - 1;
                    f[c] += wT[(size_t)((c << 6) + bit) * HIDN + h];
                    any = true;
                }
            }
        }
        double acc = 0.0;
#pragma unroll
        for (int c = 0; c < 8; ++c) acc += (double)f[c];
        float rec32 = (float)acc;

        float civ = ci[((size_t)t * NB + b) * HIDN + h];
        float cur = __fadd_rn(__fadd_rn(civ, rec32), 1e-4f);           // (in+rec)+I_APP
        float mc = __fmul_rn(2.5e5f, cur);                             // MU*cur
        pos = __fadd_rn(pos, __fmul_rn(1e-10f, mc));                   // pos += DT*(..)
        bool zbit = __fsub_rn(pos, 2.5e-8f) > 0.0f;                    // pos-W2 > 0
        pos = zbit ? 0.0f : pos;                                       // reset on fire
        unsigned long long bal = __ballot(zbit ? 1 : 0);
        if (lane == 0) zbuf[t & 1][wv] = bal;
        __syncthreads();   // publish z_t; also fences next iter's overwrite of zprev

        // ---- LI readout for step t using z_t ----
#pragma unroll
        for (int oo = 0; oo < 2; ++oo) {
            int o = (oo == 0) ? wv : (wv < 2 ? 8 + wv : -1);
            if (o < 0) continue;
            double part = 0.0;
#pragma unroll
            for (int c2 = 0; c2 < 8; ++c2) {
                if ((zbuf[t & 1][c2] >> lane) & 1ull)
                    part += (double)wout_s[o * HIDN + c2 * 64 + lane];
            }
#pragma unroll
            for (int off = 32; off > 0; off >>= 1) part += __shfl_down(part, off);
            if (lane == 0) {
                float inp = (float)part;
                float vv = (oo == 0) ? v0 : v1;
                float ii = (oo == 0) ? i0 : i1;
                float vn = __fadd_rn(vv, __fmul_rn(1e-8f, __fsub_rn(ii, vv)));
                float t2 = __fmul_rn(2e-8f, ii);
                float in2 = __fadd_rn(__fsub_rn(ii, t2), inp);
                if (oo == 0) { v0 = vn; i0 = in2; } else { v1 = vn; i1 = in2; }
                out[((size_t)t * NB + b) * NOUT + o] = vn;
            }
        }
    }
}

extern "C" void kernel_launch(void* const* d_in, const int* in_sizes, int n_in,
                              void* d_out, int out_size, void* d_ws, size_t ws_size,
                              hipStream_t stream) {
    (void)in_sizes; (void)n_in; (void)out_size;
    const float* x     = (const float*)d_in[0];
    const float* w_in  = (const float*)d_in[1];
    const float* w_rec = (const float*)d_in[2];
    const float* w_out = (const float*)d_in[3];
    float* out = (float*)d_out;
    float* ws  = (float*)d_ws;
    if (ws_size < (size_t)WS_FLOATS * 4) return;

    float* wT = ws + OFF_WT;
    float* ci = ws + OFF_CI;

    hipLaunchKernelGGL(init_kernel, dim3((HIDN * HIDN + 255) / 256), dim3(256), 0,
                       stream, wT, w_rec);
    hipLaunchKernelGGL(gemm_in, dim3(8, 400), dim3(256), 0, stream, x, w_in, ci);
    hipLaunchKernelGGL(fused_steps, dim3(NB), dim3(512), 0, stream, ci, wT, w_out, out);
}